// Round 2
// baseline (1410.258 us; speedup 1.0000x reference)
//
#include <hip/hip_runtime.h>
#include <cstdint>
#include <cstddef>

#define DI __device__ __forceinline__

typedef __bf16 bf16_t;
typedef __bf16 bf16x8 __attribute__((ext_vector_type(8)));
typedef float f32x4 __attribute__((ext_vector_type(4)));

static constexpr float SCALE = 0.17677669529663687f;  // 32^-0.5

DI bf16_t f2b(float f) {
  uint32_t u = __builtin_bit_cast(uint32_t, f);
  u += 0x7fffu + ((u >> 16) & 1u);
  return __builtin_bit_cast(bf16_t, (uint16_t)(u >> 16));
}

DI void gld16(const void* g, void* l) {
  __builtin_amdgcn_global_load_lds(
      (const __attribute__((address_space(1))) uint32_t*)g,
      (__attribute__((address_space(3))) uint32_t*)l, 16, 0, 0);
}

// ---------------- weight convert f32 -> bf16 ----------------
__global__ __launch_bounds__(256)
void cvtw(const float* __restrict__ in, bf16_t* __restrict__ out, int n) {
  int i = (blockIdx.x * 256 + threadIdx.x) * 4;
  if (i >= n) return;
  float4 v = *(const float4*)(in + i);
  ushort4 o;
  o.x = __builtin_bit_cast(uint16_t, f2b(v.x));
  o.y = __builtin_bit_cast(uint16_t, f2b(v.y));
  o.z = __builtin_bit_cast(uint16_t, f2b(v.z));
  o.w = __builtin_bit_cast(uint16_t, f2b(v.w));
  *(ushort4*)(out + i) = o;
}

// ---------------- rel-pos bias expand: [16][64][64], pad = -1e30 ----------------
__global__ __launch_bounds__(256)
void bias_pre(const float* __restrict__ rel, float* __restrict__ bf) {
  int idx = blockIdx.x * 256 + threadIdx.x;  // 65536
  int head = idx >> 12, t1 = (idx >> 6) & 63, t2 = idx & 63;
  float v = -1e30f;
  if (t1 < 49 && t2 < 49) {
    int i1 = t1 / 7, j1 = t1 - i1 * 7, i2 = t2 / 7, j2 = t2 - i2 * 7;
    v = rel[((i1 - i2 + 6) * 13 + (j1 - j2 + 6)) * 16 + head];
  }
  bf[idx] = v;
}

// ---------------- LayerNorm (+optional shift+window gather) ----------------
template<bool WIN>
__global__ __launch_bounds__(128)
void ln_kernel(const float* __restrict__ in, const float* __restrict__ g,
               const float* __restrict__ be, bf16_t* __restrict__ out)
{
  const int r = blockIdx.x;           // output row (windowed if WIN)
  const int tid = threadIdx.x;
  long srow;
  if (WIN) {
    int bw = r / 49, t = r - bw * 49;
    int b = bw >> 6, w = bw & 63;
    int wh = w >> 3, ww = w & 7;
    int i = t / 7, j = t - i * 7;
    int hs = wh * 7 + i + 3; if (hs >= 56) hs -= 56;
    int wsr = ww * 7 + j + 3; if (wsr >= 56) wsr -= 56;
    srow = (long)b * 3136 + hs * 56 + wsr;
  } else {
    srow = r;
  }
  const float4 v = *(const float4*)(in + srow * 512 + tid * 4);
  float s = v.x + v.y + v.z + v.w;
  float sq = v.x * v.x + v.y * v.y + v.z * v.z + v.w * v.w;
#pragma unroll
  for (int m = 1; m < 64; m <<= 1) { s += __shfl_xor(s, m); sq += __shfl_xor(sq, m); }
  __shared__ float ls[2], lq[2];
  if ((tid & 63) == 0) { ls[tid >> 6] = s; lq[tid >> 6] = sq; }
  __syncthreads();
  s = ls[0] + ls[1]; sq = lq[0] + lq[1];
  const float mean = s * (1.f / 512.f);
  const float rs = rsqrtf(sq * (1.f / 512.f) - mean * mean + 1e-5f);
  const float4 gg = *(const float4*)(g + tid * 4);
  const float4 bb = *(const float4*)(be + tid * 4);
  ushort4 o;
  o.x = __builtin_bit_cast(uint16_t, f2b((v.x - mean) * rs * gg.x + bb.x));
  o.y = __builtin_bit_cast(uint16_t, f2b((v.y - mean) * rs * gg.y + bb.y));
  o.z = __builtin_bit_cast(uint16_t, f2b((v.z - mean) * rs * gg.z + bb.z));
  o.w = __builtin_bit_cast(uint16_t, f2b((v.w - mean) * rs * gg.w + bb.w));
  *(ushort4*)(out + (long)r * 512 + tid * 4) = o;
}

#define MFMA16(a, b, c) __builtin_amdgcn_mfma_f32_16x16x32_bf16((a), (b), (c), 0, 0, 0)

// ---------------- persistent 256x256 8-phase GEMM -----------------------------
// C[M,N] = A[M,K]*Bw[N,K]^T, M = 100352 (392 row-tiles), grid = 256 (1/CU).
// Each block owns a contiguous chunk of output tiles (bn fastest; XCD x gets a
// contiguous range -> A/B panel L2 locality).  The m201 8-phase schedule runs
// CONTINUOUSLY across tile boundaries: staging cursors (hA/hB, 2 K-steps
// ahead) stream into the next tile while the current tile finishes + runs its
// epilogue, so there is ONE cold prologue and ONE vmcnt(0) drain per chunk
// instead of per tile.  Regions: A = (step&1)*2+half, B = 4+same; NT even so
// parity is continuous across tiles.  vmcnt(6) at each P4 forces step s+1
// fully landed (epilogue stores drain under it one phase later -- benign).
template<int EPI>
__global__ __launch_bounds__(512, 2)
void gemm256(const bf16_t* __restrict__ A, const bf16_t* __restrict__ Bw,
             const float* __restrict__ bias, const float* __restrict__ extra,
             void* __restrict__ out0, void* __restrict__ out1v, void* __restrict__ out2v,
             const int K, const int NBN)
{
  __shared__ __align__(128) bf16_t lds[8][8192];  // 128 KiB
  const int tid = threadIdx.x, lane = tid & 63, wave = tid >> 6;
  const int NT = K >> 6;
  const int ntiles = NBN * 392;

  // chunk assignment: XCD x -> chunks [32x, 32x+31] (contiguous tile range)
  const int xcd = blockIdx.x & 7, sidx = blockIdx.x >> 3;
  const int c = xcd * 32 + sidx;
  const int q2 = ntiles >> 8, r2 = ntiles & 255;
  const int t0 = c * q2 + (c < r2 ? c : r2);
  const int t1 = t0 + q2 + (c < r2 ? 1 : 0);

  // staging geometry: thread covers rows (tid>>2), (tid>>2)+128; 16B slot tid&3;
  // source chunk = slot ^ ((row>>1)&3)  (proven 0-conflict XOR swizzle)
  const int srow = tid >> 2, slot = tid & 3;
  const int chunk = slot ^ ((srow >> 1) & 3);
  const size_t rowK = (size_t)128 * K;
  const size_t PANEL = (size_t)256 * K;

  int bmC = t0 / NBN, bnC = t0 - bmC * NBN;   // compute-side tile coords

  // staging cursors (uniform): half index h -> step h>>1, half h&1
  const bf16_t* pAs = A + (size_t)(bmC * 256 + srow) * K + chunk * 8;
  const bf16_t* pBs = Bw + (size_t)(bnC * 256 + srow) * K + chunk * 8;
  int hA = 0, hB = 0, ktA = 0, hhA = 0, bnA = bnC, ktB = 0, hhB = 0, bnB = bnC;
  const int ST = (t1 - t0) * NT;
  const int hEnd = ST * 2;

#define STG_A() do { \
    if (hA < hEnd) { \
      const bf16_t* _p = pAs + ktA * 64 + hhA * 32; \
      bf16_t* _l = &lds[(ktA & 1) * 2 + hhA][tid * 8]; \
      gld16(_p, _l); gld16(_p + rowK, _l + 4096); \
      ++hA; hhA ^= 1; \
      if (!hhA) { if (++ktA == NT) { ktA = 0; if (++bnA == NBN) { bnA = 0; pAs += PANEL; } } } \
    } \
  } while (0)

#define STG_B() do { \
    if (hB < hEnd) { \
      const bf16_t* _p = pBs + ktB * 64 + hhB * 32; \
      bf16_t* _l = &lds[4 + (ktB & 1) * 2 + hhB][tid * 8]; \
      gld16(_p, _l); gld16(_p + rowK, _l + 4096); \
      ++hB; hhB ^= 1; \
      if (!hhB) { if (++ktB == NT) { ktB = 0; pBs += PANEL; if (++bnB == NBN) { bnB = 0; pBs -= (size_t)NBN * PANEL; } } } \
    } \
  } while (0)

  // fragment addressing: row stride 32 elems; chunk fkc of row R lives at
  // slot fkc ^ ((R>>1)&3); (R>>1)&3 == (fr>>1)&3 for every fragment row.
  const int fr = lane & 15, fkc = lane >> 4;
  const int wr = wave >> 2, wc = wave & 3;
  const int slotq = (fkc ^ ((fr >> 1) & 3)) << 3;
  const int aoff = (wr * 128 + fr) * 32 + slotq;  // + m*512
  const int boff = (wc * 64 + fr) * 32 + slotq;   // + n*512

  f32x4 acc[8][4] = {};
  bf16x8 af[8], bq[4];

  // prologue: A halves 0..3, B halves 0..2 (cursors then match steady state:
  // at step s, P1 stages B half 2s+3, P2 A 2s+4, P3 B 2s+4, P4 A 2s+5)
  STG_A(); STG_B(); STG_A(); STG_B(); STG_A(); STG_B(); STG_A();
  asm volatile("s_waitcnt vmcnt(6)");   // step 0 landed; step 1 (6 loads) flying
  __builtin_amdgcn_s_barrier();
  __builtin_amdgcn_sched_barrier(0);

#define PH_SYNC() \
  __builtin_amdgcn_sched_barrier(0); \
  __builtin_amdgcn_s_barrier(); \
  asm volatile("s_waitcnt lgkmcnt(0)"); \
  __builtin_amdgcn_sched_barrier(0); \
  __builtin_amdgcn_s_setprio(1)

#define PH_END() \
  __builtin_amdgcn_s_setprio(0); \
  __builtin_amdgcn_sched_barrier(0); \
  __builtin_amdgcn_s_barrier()

#define MM2(N0, N1) \
  _Pragma("unroll") \
  for (int m = 0; m < 8; ++m) { \
    acc[m][N0] = MFMA16(af[m], bq[N0], acc[m][N0]); \
    acc[m][N1] = MFMA16(af[m], bq[N1], acc[m][N1]); \
  }

#define KTILE(B) do { \
    /* ---- P1: ks=0, n={0,1} ---- */ \
    _Pragma("unroll") \
    for (int m = 0; m < 8; ++m) af[m] = *(const bf16x8*)&lds[(B) * 2][aoff + m * 512]; \
    bq[0] = *(const bf16x8*)&lds[4 + (B) * 2][boff]; \
    bq[1] = *(const bf16x8*)&lds[4 + (B) * 2][boff + 512]; \
    STG_B(); \
    PH_SYNC(); \
    MM2(0, 1); \
    PH_END(); \
    /* ---- P2: ks=0, n={2,3} ---- */ \
    bq[2] = *(const bf16x8*)&lds[4 + (B) * 2][boff + 1024]; \
    bq[3] = *(const bf16x8*)&lds[4 + (B) * 2][boff + 1536]; \
    STG_A(); \
    PH_SYNC(); \
    MM2(2, 3); \
    PH_END(); \
    /* ---- P3: ks=1, n={0,1} ---- */ \
    _Pragma("unroll") \
    for (int m = 0; m < 8; ++m) af[m] = *(const bf16x8*)&lds[(B) * 2 + 1][aoff + m * 512]; \
    bq[0] = *(const bf16x8*)&lds[4 + (B) * 2 + 1][boff]; \
    bq[1] = *(const bf16x8*)&lds[4 + (B) * 2 + 1][boff + 512]; \
    STG_B(); \
    PH_SYNC(); \
    MM2(0, 1); \
    PH_END(); \
    /* ---- P4: ks=1, n={2,3} ---- */ \
    bq[2] = *(const bf16x8*)&lds[4 + (B) * 2 + 1][boff + 1024]; \
    bq[3] = *(const bf16x8*)&lds[4 + (B) * 2 + 1][boff + 1536]; \
    STG_A(); \
    PH_SYNC(); \
    MM2(2, 3); \
    __builtin_amdgcn_s_setprio(0); \
    __builtin_amdgcn_sched_barrier(0); \
    if (sG + 2 < ST) asm volatile("s_waitcnt vmcnt(6)"); \
    else             asm volatile("s_waitcnt vmcnt(0)"); \
    __builtin_amdgcn_s_barrier(); \
    __builtin_amdgcn_sched_barrier(0); \
    ++sG; \
  } while (0)

  int sG = 0;
  const int rq = fkc * 4;
  for (int t = t0; t < t1; ++t) {
#pragma unroll 1
    for (int k2 = 0; k2 < NT; k2 += 2) {
      KTILE(0);
      KTILE(1);
    }
    // ---------------- per-tile epilogue (no LDS; staging keeps flying) ------
    {
      float bs[4];
#pragma unroll
      for (int n = 0; n < 4; ++n) bs[n] = bias[bnC * 256 + wc * 64 + n * 16 + fr];
#pragma unroll
      for (int m = 0; m < 8; ++m) {
#pragma unroll
        for (int j = 0; j < 4; ++j) {
          const int grow = bmC * 256 + wr * 128 + m * 16 + rq + j;
          long obase = 0;
          if (EPI == 0) {
            int bwi = grow / 49, t_ = grow - bwi * 49;
            obase = ((long)bwi * 784 + t_) * 32;  // + head*49*32 + d
          } else if (EPI == 1) {
            int bwi = grow / 49, t_ = grow - bwi * 49;
            int b = bwi >> 6, w = bwi & 63;
            int wh = w >> 3, ww = w & 7;
            int i = t_ / 7, jj = t_ - i * 7;
            int hs = wh * 7 + i + 3; if (hs >= 56) hs -= 56;
            int wsr = ww * 7 + jj + 3; if (wsr >= 56) wsr -= 56;
            obase = ((long)b * 3136 + hs * 56 + wsr) * 512;
          } else if (EPI == 2) {
            obase = (long)grow * 2048;
          } else {
            obase = (long)grow * 512;
          }
#pragma unroll
          for (int n = 0; n < 4; ++n) {
            const int gcol = bnC * 256 + wc * 64 + n * 16 + fr;
            float v = acc[m][n][j] + bs[n];
            if (EPI == 0) {
              int part = gcol >> 9, head = (gcol >> 5) & 15, d = gcol & 31;
              if (part == 0) v *= SCALE;
              bf16_t* dst = (bf16_t*)(part == 0 ? out0 : (part == 1 ? out1v : out2v));
              dst[obase + (long)head * 1568 + d] = f2b(v);
            } else if (EPI == 1) {
              ((float*)out0)[obase + gcol] = v + extra[obase + gcol];
            } else if (EPI == 2) {
              // tanh-form GELU via v*sigmoid(z): 7 VALU ops, 2 transcendental
              float m2 = v * v;
              float z = v * fmaf(0.07135481627f, m2, 1.59576912161f);
              float e = __expf(z);
              float rr = __builtin_amdgcn_rcpf(e + 1.0f);
              ((bf16_t*)out0)[obase + gcol] = f2b(fmaf(-v, rr, v));
            } else {
              ((float*)out0)[obase + gcol] = v + extra[obase + gcol];
            }
          }
        }
      }
#pragma unroll
      for (int m = 0; m < 8; ++m)
#pragma unroll
        for (int n = 0; n < 4; ++n) acc[m][n] = (f32x4){0.f, 0.f, 0.f, 0.f};
    }
    if (++bnC == NBN) { bnC = 0; ++bmC; }
  }
#undef KTILE
#undef MM2
#undef PH_END
#undef PH_SYNC
#undef STG_A
#undef STG_B
}

// ---------------- attention: one block per (window, head) ----------------
__global__ __launch_bounds__(256)
void attn_kernel(const bf16_t* __restrict__ qb, const bf16_t* __restrict__ kb,
                 const bf16_t* __restrict__ vb, const float* __restrict__ biasf,
                 bf16_t* __restrict__ aout)
{
  __shared__ bf16_t Q[64 * 32];
  __shared__ bf16_t Kl[64 * 32];
  __shared__ bf16_t Vt[32 * 64];
  __shared__ bf16_t Pl[4][16 * 64];
  const int bid = blockIdx.x;
  const int bw = bid >> 4, head = bid & 15;
  const int tid = threadIdx.x, lane = tid & 63, wave = tid >> 6;
  {
    uint4 z = {0u, 0u, 0u, 0u};
    *(uint4*)&Q[tid * 8] = z;
    *(uint4*)&Kl[tid * 8] = z;
    *(uint4*)&Vt[tid * 8] = z;
  }
  __syncthreads();
  const bf16_t* qsrc = qb + (long)bid * (49 * 32);
  const bf16_t* ksrc = kb + (long)bid * (49 * 32);
  const bf16_t* vsrc = vb + (long)bid * (49 * 32);
  if (tid < 196) {
    *(uint4*)&Q[tid * 8] = *(const uint4*)(qsrc + tid * 8);
    *(uint4*)&Kl[tid * 8] = *(const uint4*)(ksrc + tid * 8);
  }
  for (int e = tid; e < 1568; e += 256) {
    int t = e >> 5, d = e & 31;
    Vt[d * 64 + t] = vsrc[e];
  }
  __syncthreads();
  const int fr = lane & 15, fk = (lane >> 4) * 8, rq = (lane >> 4) * 4;
  bf16x8 aq = *(const bf16x8*)&Q[(wave * 16 + fr) * 32 + fk];
  f32x4 s[4];
#pragma unroll
  for (int n = 0; n < 4; ++n) {
    bf16x8 bk = *(const bf16x8*)&Kl[(n * 16 + fr) * 32 + fk];
    f32x4 z = {0.f, 0.f, 0.f, 0.f};
    s[n] = __builtin_amdgcn_mfma_f32_16x16x32_bf16(aq, bk, z, 0, 0, 0);
  }
  const int w = bw & 63;
  const bool wh7 = ((w >> 3) == 7), ww7 = ((w & 7) == 7);
  const float* bh = biasf + head * 4096;
#pragma unroll
  for (int j = 0; j < 4; ++j) {
    const int row = wave * 16 + rq + j;  // t1 in [0,64)
    int i1 = row / 7, j1 = row - i1 * 7;
    bool b1h = wh7 && (i1 >= 4), b1w = ww7 && (j1 >= 4);
    float pv[4];
    float mx = -3.0e38f;
#pragma unroll
    for (int n = 0; n < 4; ++n) {
      const int col = n * 16 + fr;
      float v = s[n][j] + bh[row * 64 + col];
      if (wh7 || ww7) {
        int i2 = col / 7, j2 = col - i2 * 7;
        bool b2h = wh7 && (i2 >= 4), b2w = ww7 && (j2 >= 4);
        if ((b1h != b2h) || (b1w != b2w)) v -= 100.f;
      }
      pv[n] = v;
      mx = fmaxf(mx, v);
    }
#pragma unroll
    for (int msk = 1; msk < 16; msk <<= 1) mx = fmaxf(mx, __shfl_xor(mx, msk));
    float sm = 0.f;
#pragma unroll
    for (int n = 0; n < 4; ++n) { pv[n] = __expf(pv[n] - mx); sm += pv[n]; }
#pragma unroll
    for (int msk = 1; msk < 16; msk <<= 1) sm += __shfl_xor(sm, msk);
    const float inv = 1.f / sm;
#pragma unroll
    for (int n = 0; n < 4; ++n)
      Pl[wave][(rq + j) * 64 + n * 16 + fr] = f2b(pv[n] * inv);
  }
  __syncthreads();
  f32x4 o[2] = {};
#pragma unroll
  for (int kk = 0; kk < 2; ++kk) {
    bf16x8 pa = *(const bf16x8*)&Pl[wave][fr * 64 + kk * 32 + fk];
#pragma unroll
    for (int dt = 0; dt < 2; ++dt) {
      bf16x8 vv = *(const bf16x8*)&Vt[(dt * 16 + fr) * 64 + kk * 32 + fk];
      o[dt] = __builtin_amdgcn_mfma_f32_16x16x32_bf16(pa, vv, o[dt], 0, 0, 0);
    }
  }
#pragma unroll
  for (int j = 0; j < 4; ++j) {
    const int t1 = wave * 16 + rq + j;
    if (t1 < 49) {
      bf16_t* dst = aout + ((long)bw * 49 + t1) * 512 + head * 32;
      dst[fr] = f2b(o[0][j]);
      dst[16 + fr] = f2b(o[1][j]);
    }
  }
}

// ---------------- launch ----------------
extern "C" void kernel_launch(void* const* d_in, const int* in_sizes, int n_in,
                              void* d_out, int out_size, void* d_ws, size_t ws_size,
                              hipStream_t stream)
{
  const float* x      = (const float*)d_in[0];
  const float* n1g    = (const float*)d_in[1];
  const float* n1b    = (const float*)d_in[2];
  const float* qkv_w  = (const float*)d_in[3];
  const float* qkv_b  = (const float*)d_in[4];
  const float* rel    = (const float*)d_in[5];
  const float* proj_w = (const float*)d_in[6];
  const float* proj_b = (const float*)d_in[7];
  const float* n2g    = (const float*)d_in[8];
  const float* n2b    = (const float*)d_in[9];
  const float* w1     = (const float*)d_in[10];
  const float* b1     = (const float*)d_in[11];
  const float* w2     = (const float*)d_in[12];
  const float* b2     = (const float*)d_in[13];

  char* ws = (char*)d_ws;
  bf16_t* Wqkv  = (bf16_t*)(ws + 0);          // 1536*512*2 = 1572864
  bf16_t* Wproj = (bf16_t*)(ws + 1572864);    // 512*512*2  = 524288
  bf16_t* Wm1   = (bf16_t*)(ws + 2097152);    // 2048*512*2 = 2097152
  bf16_t* Wm2   = (bf16_t*)(ws + 4194304);    // 512*2048*2 = 2097152
  float*  biasf = (float*)(ws + 6291456);     // 16*64*64*4 = 1048576
  const size_t ABYTES = (size_t)100352 * 512 * 2;  // 102760448
  const size_t P1 = 8388608;
  const size_t P2 = P1 + ABYTES + 1048576;         // 112197632
  bf16_t* xw      = (bf16_t*)(ws + P1);
  bf16_t* qbuf    = (bf16_t*)(ws + P2);
  bf16_t* kbuf    = (bf16_t*)(ws + P2 + ABYTES);
  bf16_t* vbuf    = (bf16_t*)(ws + P2 + 2 * ABYTES);
  bf16_t* attnout = xw;       // reuse after QKV gemm consumed xw
  bf16_t* h2      = xw;       // reuse after proj consumed attnout
  bf16_t* hidden  = qbuf;     // reuse q/k/v (+spare) after attention

  cvtw<<<768, 256, 0, stream>>>(qkv_w, Wqkv, 1536 * 512);
  cvtw<<<256, 256, 0, stream>>>(proj_w, Wproj, 512 * 512);
  cvtw<<<1024, 256, 0, stream>>>(w1, Wm1, 2048 * 512);
  cvtw<<<1024, 256, 0, stream>>>(w2, Wm2, 512 * 2048);
  bias_pre<<<256, 256, 0, stream>>>(rel, biasf);

  ln_kernel<true><<<100352, 128, 0, stream>>>(x, n1g, n1b, xw);
  gemm256<0><<<256, 512, 0, stream>>>(xw, Wqkv, qkv_b, nullptr,
                                      qbuf, kbuf, vbuf, 512, 6);
  attn_kernel<<<32768, 256, 0, stream>>>(qbuf, kbuf, vbuf, biasf, attnout);
  gemm256<1><<<256, 512, 0, stream>>>(attnout, Wproj, proj_b, x,
                                      d_out, nullptr, nullptr, 512, 2);
  ln_kernel<false><<<100352, 128, 0, stream>>>((const float*)d_out, n2g, n2b, h2);
  gemm256<2><<<256, 512, 0, stream>>>(h2, Wm1, b1, nullptr,
                                      hidden, nullptr, nullptr, 512, 8);
  gemm256<3><<<256, 512, 0, stream>>>(hidden, Wm2, b2, (const float*)d_out,
                                      d_out, nullptr, nullptr, 2048, 2);
}

// Round 3
// 1314.242 us; speedup vs baseline: 1.0731x; 1.0731x over previous
//
#include <hip/hip_runtime.h>
#include <cstdint>
#include <cstddef>

#define DI __device__ __forceinline__

typedef __bf16 bf16_t;
typedef __bf16 bf16x8 __attribute__((ext_vector_type(8)));
typedef float f32x4 __attribute__((ext_vector_type(4)));

static constexpr float SCALE = 0.17677669529663687f;  // 32^-0.5

DI bf16_t f2b(float f) {
  uint32_t u = __builtin_bit_cast(uint32_t, f);
  u += 0x7fffu + ((u >> 16) & 1u);
  return __builtin_bit_cast(bf16_t, (uint16_t)(u >> 16));
}

DI void gld16(const void* g, void* l) {
  __builtin_amdgcn_global_load_lds(
      (const __attribute__((address_space(1))) uint32_t*)g,
      (__attribute__((address_space(3))) uint32_t*)l, 16, 0, 0);
}

// ---------------- weight convert f32 -> bf16 ----------------
__global__ __launch_bounds__(256)
void cvtw(const float* __restrict__ in, bf16_t* __restrict__ out, int n) {
  int i = (blockIdx.x * 256 + threadIdx.x) * 4;
  if (i >= n) return;
  float4 v = *(const float4*)(in + i);
  ushort4 o;
  o.x = __builtin_bit_cast(uint16_t, f2b(v.x));
  o.y = __builtin_bit_cast(uint16_t, f2b(v.y));
  o.z = __builtin_bit_cast(uint16_t, f2b(v.z));
  o.w = __builtin_bit_cast(uint16_t, f2b(v.w));
  *(ushort4*)(out + i) = o;
}

// ---------------- rel-pos bias expand: [16][64][64], pad = -1e30 ----------------
__global__ __launch_bounds__(256)
void bias_pre(const float* __restrict__ rel, float* __restrict__ bf) {
  int idx = blockIdx.x * 256 + threadIdx.x;  // 65536
  int head = idx >> 12, t1 = (idx >> 6) & 63, t2 = idx & 63;
  float v = -1e30f;
  if (t1 < 49 && t2 < 49) {
    int i1 = t1 / 7, j1 = t1 - i1 * 7, i2 = t2 / 7, j2 = t2 - i2 * 7;
    v = rel[((i1 - i2 + 6) * 13 + (j1 - j2 + 6)) * 16 + head];
  }
  bf[idx] = v;
}

// ---------------- LayerNorm (+optional shift+window gather) ----------------
template<bool WIN>
__global__ __launch_bounds__(128)
void ln_kernel(const float* __restrict__ in, const float* __restrict__ g,
               const float* __restrict__ be, bf16_t* __restrict__ out)
{
  const int r = blockIdx.x;           // output row (windowed if WIN)
  const int tid = threadIdx.x;
  long srow;
  if (WIN) {
    int bw = r / 49, t = r - bw * 49;
    int b = bw >> 6, w = bw & 63;
    int wh = w >> 3, ww = w & 7;
    int i = t / 7, j = t - i * 7;
    int hs = wh * 7 + i + 3; if (hs >= 56) hs -= 56;
    int wsr = ww * 7 + j + 3; if (wsr >= 56) wsr -= 56;
    srow = (long)b * 3136 + hs * 56 + wsr;
  } else {
    srow = r;
  }
  const float4 v = *(const float4*)(in + srow * 512 + tid * 4);
  float s = v.x + v.y + v.z + v.w;
  float sq = v.x * v.x + v.y * v.y + v.z * v.z + v.w * v.w;
#pragma unroll
  for (int m = 1; m < 64; m <<= 1) { s += __shfl_xor(s, m); sq += __shfl_xor(sq, m); }
  __shared__ float ls[2], lq[2];
  if ((tid & 63) == 0) { ls[tid >> 6] = s; lq[tid >> 6] = sq; }
  __syncthreads();
  s = ls[0] + ls[1]; sq = lq[0] + lq[1];
  const float mean = s * (1.f / 512.f);
  const float rs = rsqrtf(sq * (1.f / 512.f) - mean * mean + 1e-5f);
  const float4 gg = *(const float4*)(g + tid * 4);
  const float4 bb = *(const float4*)(be + tid * 4);
  ushort4 o;
  o.x = __builtin_bit_cast(uint16_t, f2b((v.x - mean) * rs * gg.x + bb.x));
  o.y = __builtin_bit_cast(uint16_t, f2b((v.y - mean) * rs * gg.y + bb.y));
  o.z = __builtin_bit_cast(uint16_t, f2b((v.z - mean) * rs * gg.z + bb.z));
  o.w = __builtin_bit_cast(uint16_t, f2b((v.w - mean) * rs * gg.w + bb.w));
  *(ushort4*)(out + (long)r * 512 + tid * 4) = o;
}

#define MFMA16(a, b, c) __builtin_amdgcn_mfma_f32_16x16x32_bf16((a), (b), (c), 0, 0, 0)

// ---------------- persistent 256x256 8-phase GEMM, L2-coherent tile walk ------
// C[M,N] = A[M,K]*Bw[N,K]^T, M = 100352 (392 bm-tiles), grid = 256 (1/CU).
// XCD x owns bm in [49x, 49x+49).  Block j (= blockIdx>>3) takes FIXED
// bn = j%NBN and walks bm = 49x + j/NBN + s*G, G = 32/NBN.  The G*NBN
// co-running blocks of an XCD always cover {G consecutive bm} x {all bn}:
// each A-panel is L2-shared by NBN blocks, B-panels stay L2-resident and are
// re-staged from L2 every tile.  One prologue + one vmcnt(0) drain per BLOCK
// (not per tile); staging cursors stream continuously across tile boundaries
// so each tile's epilogue overlaps the next tile's in-flight loads.
// Regions: A = (kt&1)*2+half, B = 4+same; NT even -> parity continuous.
template<int EPI>
__global__ __launch_bounds__(512, 2)
void gemm256(const bf16_t* __restrict__ A, const bf16_t* __restrict__ Bw,
             const float* __restrict__ bias, const float* __restrict__ extra,
             void* __restrict__ out0, void* __restrict__ out1v, void* __restrict__ out2v,
             const int K, const int NBN)
{
  __shared__ __align__(128) bf16_t lds[8][8192];  // 128 KiB
  const int tid = threadIdx.x, lane = tid & 63, wave = tid >> 6;
  const int NT = K >> 6;

  const int xcd = blockIdx.x & 7, j = blockIdx.x >> 3;
  const int G = 32 / NBN;
  if (j >= G * NBN) return;               // idle only when NBN=6 (2 of 32)
  const int bmo = j / NBN;
  const int bn = j - bmo * NBN;           // fixed per block
  const int m0 = xcd * 49;
  const int tiles = (49 - bmo + G - 1) / G;
  const int ST = tiles * NT;
  const int hEnd = 2 * ST;

  // staging geometry: thread covers rows (tid>>2), (tid>>2)+128; 16B slot tid&3;
  // source chunk = slot ^ ((row>>1)&3)  (proven 0-conflict XOR swizzle)
  const int srow = tid >> 2, slot = tid & 3;
  const int chunk = slot ^ ((srow >> 1) & 3);
  const size_t rowK = (size_t)128 * K;
  const size_t strideA = (size_t)G * 256 * K;

  const bf16_t* pAs = A + ((size_t)(m0 + bmo) * 256 + srow) * K + chunk * 8;
  const bf16_t* pBs = Bw + ((size_t)bn * 256 + srow) * K + chunk * 8;
  int hA = 0, hB = 0, ktA = 0, hhA = 0, ktB = 0, hhB = 0;

#define STG_A() do { \
    if (hA < hEnd) { \
      const bf16_t* _p = pAs + ktA * 64 + hhA * 32; \
      bf16_t* _l = &lds[(ktA & 1) * 2 + hhA][tid * 8]; \
      gld16(_p, _l); gld16(_p + rowK, _l + 4096); \
      ++hA; hhA ^= 1; \
      if (!hhA) { if (++ktA == NT) { ktA = 0; pAs += strideA; } } \
    } \
  } while (0)

#define STG_B() do { \
    if (hB < hEnd) { \
      const bf16_t* _p = pBs + ktB * 64 + hhB * 32; \
      bf16_t* _l = &lds[4 + (ktB & 1) * 2 + hhB][tid * 8]; \
      gld16(_p, _l); gld16(_p + rowK, _l + 4096); \
      ++hB; hhB ^= 1; \
      if (!hhB) { if (++ktB == NT) ktB = 0; }  /* same bn panel every tile */ \
    } \
  } while (0)

  // fragment addressing: row stride 32 elems; chunk fkc of row R lives at
  // slot fkc ^ ((R>>1)&3); (R>>1)&3 == (fr>>1)&3 for every fragment row.
  const int fr = lane & 15, fkc = lane >> 4;
  const int wr = wave >> 2, wc = wave & 3;
  const int slotq = (fkc ^ ((fr >> 1) & 3)) << 3;
  const int aoff = (wr * 128 + fr) * 32 + slotq;  // + m*512
  const int boff = (wc * 64 + fr) * 32 + slotq;   // + n*512

  f32x4 acc[8][4] = {};
  bf16x8 af[8], bq[4];

  // prologue: A halves 0..3, B halves 0..2 (cursors then match steady state:
  // at step s, P1 stages B half 2s+3, P2 A 2s+4, P3 B 2s+4, P4 A 2s+5)
  STG_A(); STG_B(); STG_A(); STG_B(); STG_A(); STG_B(); STG_A();
  asm volatile("s_waitcnt vmcnt(6)");   // step 0 landed; step 1 (6 loads) flying
  __builtin_amdgcn_s_barrier();
  __builtin_amdgcn_sched_barrier(0);

#define PH_SYNC() \
  __builtin_amdgcn_sched_barrier(0); \
  __builtin_amdgcn_s_barrier(); \
  asm volatile("s_waitcnt lgkmcnt(0)"); \
  __builtin_amdgcn_sched_barrier(0); \
  __builtin_amdgcn_s_setprio(1)

#define PH_END() \
  __builtin_amdgcn_s_setprio(0); \
  __builtin_amdgcn_sched_barrier(0); \
  __builtin_amdgcn_s_barrier()

#define MM2(N0, N1) \
  _Pragma("unroll") \
  for (int m = 0; m < 8; ++m) { \
    acc[m][N0] = MFMA16(af[m], bq[N0], acc[m][N0]); \
    acc[m][N1] = MFMA16(af[m], bq[N1], acc[m][N1]); \
  }

#define KTILE(B) do { \
    /* ---- P1: ks=0, n={0,1} ---- */ \
    _Pragma("unroll") \
    for (int m = 0; m < 8; ++m) af[m] = *(const bf16x8*)&lds[(B) * 2][aoff + m * 512]; \
    bq[0] = *(const bf16x8*)&lds[4 + (B) * 2][boff]; \
    bq[1] = *(const bf16x8*)&lds[4 + (B) * 2][boff + 512]; \
    STG_B(); \
    PH_SYNC(); \
    MM2(0, 1); \
    PH_END(); \
    /* ---- P2: ks=0, n={2,3} ---- */ \
    bq[2] = *(const bf16x8*)&lds[4 + (B) * 2][boff + 1024]; \
    bq[3] = *(const bf16x8*)&lds[4 + (B) * 2][boff + 1536]; \
    STG_A(); \
    PH_SYNC(); \
    MM2(2, 3); \
    PH_END(); \
    /* ---- P3: ks=1, n={0,1} ---- */ \
    _Pragma("unroll") \
    for (int m = 0; m < 8; ++m) af[m] = *(const bf16x8*)&lds[(B) * 2 + 1][aoff + m * 512]; \
    bq[0] = *(const bf16x8*)&lds[4 + (B) * 2 + 1][boff]; \
    bq[1] = *(const bf16x8*)&lds[4 + (B) * 2 + 1][boff + 512]; \
    STG_B(); \
    PH_SYNC(); \
    MM2(0, 1); \
    PH_END(); \
    /* ---- P4: ks=1, n={2,3} ---- */ \
    bq[2] = *(const bf16x8*)&lds[4 + (B) * 2 + 1][boff + 1024]; \
    bq[3] = *(const bf16x8*)&lds[4 + (B) * 2 + 1][boff + 1536]; \
    STG_A(); \
    PH_SYNC(); \
    MM2(2, 3); \
    __builtin_amdgcn_s_setprio(0); \
    __builtin_amdgcn_sched_barrier(0); \
    if (sG + 2 < ST) asm volatile("s_waitcnt vmcnt(6)"); \
    else             asm volatile("s_waitcnt vmcnt(0)"); \
    __builtin_amdgcn_s_barrier(); \
    __builtin_amdgcn_sched_barrier(0); \
    ++sG; \
  } while (0)

  int sG = 0;
  int bmC = m0 + bmo;
  const int rq = fkc * 4;
  float bs[4];
#pragma unroll
  for (int n = 0; n < 4; ++n) bs[n] = bias[bn * 256 + wc * 64 + n * 16 + fr];

  for (int t = 0; t < tiles; ++t) {
#pragma unroll 1
    for (int k2 = 0; k2 < NT; k2 += 2) {
      KTILE(0);
      KTILE(1);
    }
    // ---------------- per-tile epilogue (no LDS; staging keeps flying) ------
#pragma unroll
    for (int m = 0; m < 8; ++m) {
#pragma unroll
      for (int jj4 = 0; jj4 < 4; ++jj4) {
        const int grow = bmC * 256 + wr * 128 + m * 16 + rq + jj4;
        long obase = 0;
        if (EPI == 0) {
          int bwi = grow / 49, t_ = grow - bwi * 49;
          obase = ((long)bwi * 784 + t_) * 32;  // + head*49*32 + d
        } else if (EPI == 1) {
          int bwi = grow / 49, t_ = grow - bwi * 49;
          int b = bwi >> 6, w = bwi & 63;
          int wh = w >> 3, ww = w & 7;
          int i = t_ / 7, jj = t_ - i * 7;
          int hs = wh * 7 + i + 3; if (hs >= 56) hs -= 56;
          int wsr = ww * 7 + jj + 3; if (wsr >= 56) wsr -= 56;
          obase = ((long)b * 3136 + hs * 56 + wsr) * 512;
        } else if (EPI == 2) {
          obase = (long)grow * 2048;
        } else {
          obase = (long)grow * 512;
        }
#pragma unroll
        for (int n = 0; n < 4; ++n) {
          const int gcol = bn * 256 + wc * 64 + n * 16 + fr;
          float v = acc[m][n][jj4] + bs[n];
          if (EPI == 0) {
            int part = gcol >> 9, head = (gcol >> 5) & 15, d = gcol & 31;
            if (part == 0) v *= SCALE;
            bf16_t* dst = (bf16_t*)(part == 0 ? out0 : (part == 1 ? out1v : out2v));
            dst[obase + (long)head * 1568 + d] = f2b(v);
          } else if (EPI == 1) {
            ((float*)out0)[obase + gcol] = v + extra[obase + gcol];
          } else if (EPI == 2) {
            // tanh-form GELU via v*sigmoid(z): 7 VALU ops, 2 transcendental
            float m2 = v * v;
            float z = v * fmaf(0.07135481627f, m2, 1.59576912161f);
            float e = __expf(z);
            float rr = __builtin_amdgcn_rcpf(e + 1.0f);
            ((bf16_t*)out0)[obase + gcol] = f2b(fmaf(-v, rr, v));
          } else {
            ((float*)out0)[obase + gcol] = v + extra[obase + gcol];
          }
        }
      }
    }
#pragma unroll
    for (int m = 0; m < 8; ++m)
#pragma unroll
      for (int n = 0; n < 4; ++n) acc[m][n] = (f32x4){0.f, 0.f, 0.f, 0.f};
    bmC += G;
  }
#undef KTILE
#undef MM2
#undef PH_END
#undef PH_SYNC
#undef STG_A
#undef STG_B
}

// ---------------- attention: one block per (window, head) ----------------
__global__ __launch_bounds__(256)
void attn_kernel(const bf16_t* __restrict__ qb, const bf16_t* __restrict__ kb,
                 const bf16_t* __restrict__ vb, const float* __restrict__ biasf,
                 bf16_t* __restrict__ aout)
{
  __shared__ bf16_t Q[64 * 32];
  __shared__ bf16_t Kl[64 * 32];
  __shared__ bf16_t Vt[32 * 64];
  __shared__ bf16_t Pl[4][16 * 64];
  const int bid = blockIdx.x;
  const int bw = bid >> 4, head = bid & 15;
  const int tid = threadIdx.x, lane = tid & 63, wave = tid >> 6;
  {
    uint4 z = {0u, 0u, 0u, 0u};
    *(uint4*)&Q[tid * 8] = z;
    *(uint4*)&Kl[tid * 8] = z;
    *(uint4*)&Vt[tid * 8] = z;
  }
  __syncthreads();
  const bf16_t* qsrc = qb + (long)bid * (49 * 32);
  const bf16_t* ksrc = kb + (long)bid * (49 * 32);
  const bf16_t* vsrc = vb + (long)bid * (49 * 32);
  if (tid < 196) {
    *(uint4*)&Q[tid * 8] = *(const uint4*)(qsrc + tid * 8);
    *(uint4*)&Kl[tid * 8] = *(const uint4*)(ksrc + tid * 8);
  }
  for (int e = tid; e < 1568; e += 256) {
    int t = e >> 5, d = e & 31;
    Vt[d * 64 + t] = vsrc[e];
  }
  __syncthreads();
  const int fr = lane & 15, fk = (lane >> 4) * 8, rq = (lane >> 4) * 4;
  bf16x8 aq = *(const bf16x8*)&Q[(wave * 16 + fr) * 32 + fk];
  f32x4 s[4];
#pragma unroll
  for (int n = 0; n < 4; ++n) {
    bf16x8 bk = *(const bf16x8*)&Kl[(n * 16 + fr) * 32 + fk];
    f32x4 z = {0.f, 0.f, 0.f, 0.f};
    s[n] = __builtin_amdgcn_mfma_f32_16x16x32_bf16(aq, bk, z, 0, 0, 0);
  }
  const int w = bw & 63;
  const bool wh7 = ((w >> 3) == 7), ww7 = ((w & 7) == 7);
  const float* bh = biasf + head * 4096;
#pragma unroll
  for (int j = 0; j < 4; ++j) {
    const int row = wave * 16 + rq + j;  // t1 in [0,64)
    int i1 = row / 7, j1 = row - i1 * 7;
    bool b1h = wh7 && (i1 >= 4), b1w = ww7 && (j1 >= 4);
    float pv[4];
    float mx = -3.0e38f;
#pragma unroll
    for (int n = 0; n < 4; ++n) {
      const int col = n * 16 + fr;
      float v = s[n][j] + bh[row * 64 + col];
      if (wh7 || ww7) {
        int i2 = col / 7, j2 = col - i2 * 7;
        bool b2h = wh7 && (i2 >= 4), b2w = ww7 && (j2 >= 4);
        if ((b1h != b2h) || (b1w != b2w)) v -= 100.f;
      }
      pv[n] = v;
      mx = fmaxf(mx, v);
    }
#pragma unroll
    for (int msk = 1; msk < 16; msk <<= 1) mx = fmaxf(mx, __shfl_xor(mx, msk));
    float sm = 0.f;
#pragma unroll
    for (int n = 0; n < 4; ++n) { pv[n] = __expf(pv[n] - mx); sm += pv[n]; }
#pragma unroll
    for (int msk = 1; msk < 16; msk <<= 1) sm += __shfl_xor(sm, msk);
    const float inv = 1.f / sm;
#pragma unroll
    for (int n = 0; n < 4; ++n)
      Pl[wave][(rq + j) * 64 + n * 16 + fr] = f2b(pv[n] * inv);
  }
  __syncthreads();
  f32x4 o[2] = {};
#pragma unroll
  for (int kk = 0; kk < 2; ++kk) {
    bf16x8 pa = *(const bf16x8*)&Pl[wave][fr * 64 + kk * 32 + fk];
#pragma unroll
    for (int dt = 0; dt < 2; ++dt) {
      bf16x8 vv = *(const bf16x8*)&Vt[(dt * 16 + fr) * 64 + kk * 32 + fk];
      o[dt] = __builtin_amdgcn_mfma_f32_16x16x32_bf16(pa, vv, o[dt], 0, 0, 0);
    }
  }
#pragma unroll
  for (int j = 0; j < 4; ++j) {
    const int t1 = wave * 16 + rq + j;
    if (t1 < 49) {
      bf16_t* dst = aout + ((long)bw * 49 + t1) * 512 + head * 32;
      dst[fr] = f2b(o[0][j]);
      dst[16 + fr] = f2b(o[1][j]);
    }
  }
}

// ---------------- launch ----------------
extern "C" void kernel_launch(void* const* d_in, const int* in_sizes, int n_in,
                              void* d_out, int out_size, void* d_ws, size_t ws_size,
                              hipStream_t stream)
{
  const float* x      = (const float*)d_in[0];
  const float* n1g    = (const float*)d_in[1];
  const float* n1b    = (const float*)d_in[2];
  const float* qkv_w  = (const float*)d_in[3];
  const float* qkv_b  = (const float*)d_in[4];
  const float* rel    = (const float*)d_in[5];
  const float* proj_w = (const float*)d_in[6];
  const float* proj_b = (const float*)d_in[7];
  const float* n2g    = (const float*)d_in[8];
  const float* n2b    = (const float*)d_in[9];
  const float* w1     = (const float*)d_in[10];
  const float* b1     = (const float*)d_in[11];
  const float* w2     = (const float*)d_in[12];
  const float* b2     = (const float*)d_in[13];

  char* ws = (char*)d_ws;
  bf16_t* Wqkv  = (bf16_t*)(ws + 0);          // 1536*512*2 = 1572864
  bf16_t* Wproj = (bf16_t*)(ws + 1572864);    // 512*512*2  = 524288
  bf16_t* Wm1   = (bf16_t*)(ws + 2097152);    // 2048*512*2 = 2097152
  bf16_t* Wm2   = (bf16_t*)(ws + 4194304);    // 512*2048*2 = 2097152
  float*  biasf = (float*)(ws + 6291456);     // 16*64*64*4 = 1048576
  const size_t ABYTES = (size_t)100352 * 512 * 2;  // 102760448
  const size_t P1 = 8388608;
  const size_t P2 = P1 + ABYTES + 1048576;         // 112197632
  bf16_t* xw      = (bf16_t*)(ws + P1);
  bf16_t* qbuf    = (bf16_t*)(ws + P2);
  bf16_t* kbuf    = (bf16_t*)(ws + P2 + ABYTES);
  bf16_t* vbuf    = (bf16_t*)(ws + P2 + 2 * ABYTES);
  bf16_t* attnout = xw;       // reuse after QKV gemm consumed xw
  bf16_t* h2      = xw;       // reuse after proj consumed attnout
  bf16_t* hidden  = qbuf;     // reuse q/k/v (+spare) after attention

  cvtw<<<768, 256, 0, stream>>>(qkv_w, Wqkv, 1536 * 512);
  cvtw<<<256, 256, 0, stream>>>(proj_w, Wproj, 512 * 512);
  cvtw<<<1024, 256, 0, stream>>>(w1, Wm1, 2048 * 512);
  cvtw<<<1024, 256, 0, stream>>>(w2, Wm2, 512 * 2048);
  bias_pre<<<256, 256, 0, stream>>>(rel, biasf);

  ln_kernel<true><<<100352, 128, 0, stream>>>(x, n1g, n1b, xw);
  gemm256<0><<<256, 512, 0, stream>>>(xw, Wqkv, qkv_b, nullptr,
                                      qbuf, kbuf, vbuf, 512, 6);
  attn_kernel<<<32768, 256, 0, stream>>>(qbuf, kbuf, vbuf, biasf, attnout);
  gemm256<1><<<256, 512, 0, stream>>>(attnout, Wproj, proj_b, x,
                                      d_out, nullptr, nullptr, 512, 2);
  ln_kernel<false><<<100352, 128, 0, stream>>>((const float*)d_out, n2g, n2b, h2);
  gemm256<2><<<256, 512, 0, stream>>>(h2, Wm1, b1, nullptr,
                                      hidden, nullptr, nullptr, 512, 8);
  gemm256<3><<<256, 512, 0, stream>>>(hidden, Wm2, b2, (const float*)d_out,
                                      d_out, nullptr, nullptr, 2048, 2);
}